// Round 1
// baseline (163.475 us; speedup 1.0000x reference)
//
#include <hip/hip_runtime.h>

#define KDIM 64
#define ROWS_PER_BLOCK 4

__global__ __launch_bounds__(256) void rankdpo_main(
    const float* __restrict__ s_in, const float* __restrict__ r_in,
    float* __restrict__ partials, int B)
{
    const int wave = threadIdx.x >> 6;
    const int lane = threadIdx.x & 63;
    const int row  = blockIdx.x * ROWS_PER_BLOCK + wave;

    float acc = 0.0f;
    if (row < B) {
        const float s = s_in[row * KDIM + lane];
        const float r = r_in[row * KDIM + lane];

        // 1-based rank when rewards sorted descending, stable (index tiebreak)
        int cnt = 0;
        #pragma unroll
        for (int j = 0; j < KDIM; ++j) {
            float rj = __shfl(r, j);
            cnt += (rj > r) || (rj == r && j < lane);
        }
        const float invd = 1.0f / log1pf((float)(cnt + 1));
        const float g    = 2.0f * r - 1.0f;

        // pairwise: sum over i > j of |g_i-g_j|*|d_i-d_j| * log_sigmoid(s_j - s_i)
        for (int j = 0; j < KDIM; ++j) {
            float gj = __shfl(g, j);
            float dj = __shfl(invd, j);
            float sj = __shfl(s, j);
            float delta = fabsf(g - gj) * fabsf(invd - dj);
            float diff  = s - sj;                          // s_i - s_j
            // log_sigmoid(-diff) = -softplus(diff) = -(max(diff,0)+log1p(exp(-|diff|)))
            float lsig  = -(fmaxf(diff, 0.0f) + log1pf(expf(-fabsf(diff))));
            acc += (lane > j) ? delta * lsig : 0.0f;
        }
    }

    // wave reduction (64 lanes)
    #pragma unroll
    for (int off = 32; off > 0; off >>= 1)
        acc += __shfl_down(acc, off);

    __shared__ float wsum[ROWS_PER_BLOCK];
    if (lane == 0) wsum[wave] = acc;
    __syncthreads();
    if (threadIdx.x == 0)
        partials[blockIdx.x] = wsum[0] + wsum[1] + wsum[2] + wsum[3];
}

__global__ __launch_bounds__(256) void rankdpo_reduce(
    const float* __restrict__ partials, int n, float* __restrict__ out,
    double neg_inv_count)
{
    double sum = 0.0;
    for (int i = threadIdx.x; i < n; i += 256)
        sum += (double)partials[i];
    __shared__ double sh[256];
    sh[threadIdx.x] = sum;
    __syncthreads();
    for (int st = 128; st > 0; st >>= 1) {
        if (threadIdx.x < st) sh[threadIdx.x] += sh[threadIdx.x + st];
        __syncthreads();
    }
    if (threadIdx.x == 0)
        out[0] = (float)(sh[0] * neg_inv_count);
}

extern "C" void kernel_launch(void* const* d_in, const int* in_sizes, int n_in,
                              void* d_out, int out_size, void* d_ws, size_t ws_size,
                              hipStream_t stream) {
    const float* s = (const float*)d_in[0];   // policy_logps [B,K] f32
    const float* r = (const float*)d_in[1];   // reward_scores [B,K] f32
    float* out = (float*)d_out;

    const int BK = in_sizes[0];
    const int B  = BK / KDIM;
    const int nblocks = (B + ROWS_PER_BLOCK - 1) / ROWS_PER_BLOCK;

    float* partials = (float*)d_ws;  // nblocks floats, all written before read

    const long long count = (long long)B * (KDIM * (KDIM - 1) / 2);
    const double neg_inv_count = -1.0 / (double)count;

    rankdpo_main<<<nblocks, 256, 0, stream>>>(s, r, partials, B);
    rankdpo_reduce<<<1, 256, 0, stream>>>(partials, nblocks, out, neg_inv_count);
}

// Round 2
// 109.671 us; speedup vs baseline: 1.4906x; 1.4906x over previous
//
#include <hip/hip_runtime.h>

#define KDIM 64
#define ROWS_PER_BLOCK 4

__global__ __launch_bounds__(256) void rankdpo_fused(
    const float* __restrict__ s_in, const float* __restrict__ r_in,
    float* __restrict__ out, double* __restrict__ ws_sum,
    unsigned int* __restrict__ ws_cnt, int B, double inv_count,
    unsigned int nblocks)
{
    const int wave = threadIdx.x >> 6;
    const int lane = threadIdx.x & 63;
    const int row  = blockIdx.x * ROWS_PER_BLOCK + wave;
    const int rrow = row < B ? row : B - 1;

    const float s = s_in[rrow * KDIM + lane];
    const float r = r_in[rrow * KDIM + lane];

    // 1-based descending rank, stable tiebreak by index (matches jnp argsort-argsort)
    int cnt = 0;
    #pragma unroll
    for (int j = 0; j < KDIM; ++j) {
        float rj = __uint_as_float(__builtin_amdgcn_readlane(__float_as_uint(r), j));
        cnt += (rj > r) || (rj == r && j < lane);
    }
    // invd = 1/log1p(rank); rank = cnt+1 integer -> log1p(rank) = ln(cnt+2)
    const float invd = __builtin_amdgcn_rcpf(
        0.69314718056f * __builtin_amdgcn_logf((float)(cnt + 2)));
    const float g = 2.0f * r - 1.0f;

    // Rotation covering of the strict triangle:
    //   d=1..31: pairs {i,(i-d)&63} are each unordered pair exactly once, all
    //   lanes useful. d=32: each pair appears twice (i and i^32) -> keep lane>=32.
    // Accumulate pacc = sum delta * softplus(s_hi - s_lo) (hi/lo = larger/smaller
    // index); reference returns +pacc/count.
    float pacc = 0.0f;
    #pragma unroll
    for (int d = 1; d <= 32; ++d) {
        int pj = (lane - d) & 63;
        float sj = __shfl(s, pj);
        float gj = __shfl(g, pj);
        float dj = __shfl(invd, pj);
        float delta = fabsf(g - gj) * fabsf(invd - dj);
        float u = (lane >= d) ? (s - sj) : (sj - s);  // s_largerIdx - s_smallerIdx
        // softplus(u) = max(u,0) + ln2 * log2(1 + 2^(-|u|*log2e))
        float e  = __builtin_amdgcn_exp2f(-1.44269504089f * fabsf(u));
        float sp = fmaxf(u, 0.0f) + 0.69314718056f * __builtin_amdgcn_logf(1.0f + e);
        if (d == 32 && lane < 32) delta = 0.0f;
        pacc = fmaf(delta, sp, pacc);
    }
    if (row >= B) pacc = 0.0f;

    // wave reduction (64 lanes)
    #pragma unroll
    for (int off = 32; off > 0; off >>= 1)
        pacc += __shfl_down(pacc, off);

    __shared__ float wsum[ROWS_PER_BLOCK];
    if (lane == 0) wsum[wave] = pacc;
    __syncthreads();
    if (threadIdx.x == 0) {
        double bsum = (double)wsum[0] + (double)wsum[1] +
                      (double)wsum[2] + (double)wsum[3];
        atomicAdd(ws_sum, bsum);
        __threadfence();
        unsigned int old = atomicAdd(ws_cnt, 1u);
        if (old == nblocks - 1) {
            double tot = atomicAdd(ws_sum, 0.0);  // safe re-read after fence
            out[0] = (float)(tot * inv_count);
        }
    }
}

extern "C" void kernel_launch(void* const* d_in, const int* in_sizes, int n_in,
                              void* d_out, int out_size, void* d_ws, size_t ws_size,
                              hipStream_t stream) {
    const float* s = (const float*)d_in[0];   // policy_logps [B,K] f32
    const float* r = (const float*)d_in[1];   // reward_scores [B,K] f32
    float* out = (float*)d_out;

    const int BK = in_sizes[0];
    const int B  = BK / KDIM;
    const unsigned int nblocks = (B + ROWS_PER_BLOCK - 1) / ROWS_PER_BLOCK;

    double* ws_sum = (double*)d_ws;                    // 8 B
    unsigned int* ws_cnt = (unsigned int*)((char*)d_ws + 8);  // 4 B

    const long long count = (long long)B * (KDIM * (KDIM - 1) / 2);
    const double inv_count = 1.0 / (double)count;

    hipMemsetAsync(d_ws, 0, 16, stream);  // zero sum + counter (capture-safe)
    rankdpo_fused<<<nblocks, 256, 0, stream>>>(s, r, out, ws_sum, ws_cnt,
                                               B, inv_count, nblocks);
}

// Round 3
// 72.039 us; speedup vs baseline: 2.2693x; 1.5224x over previous
//
#include <hip/hip_runtime.h>

#define KDIM 64
#define WAVES_PER_BLOCK 4
#define ROWS_PER_WAVE 2
#define ROWS_PER_BLOCK (WAVES_PER_BLOCK * ROWS_PER_WAVE)  // 8

__global__ __launch_bounds__(256) void rankdpo_main(
    const float* __restrict__ s_in, const float* __restrict__ r_in,
    float* __restrict__ partials, int B)
{
    const int wave = threadIdx.x >> 6;
    const int lane = threadIdx.x & 63;
    const int row0 = blockIdx.x * ROWS_PER_BLOCK + wave * ROWS_PER_WAVE;
    const int row1 = row0 + 1;
    const int a0 = (row0 < B ? row0 : 0) * KDIM + lane;
    const int a1 = (row1 < B ? row1 : 0) * KDIM + lane;

    const float s0 = s_in[a0], r0 = r_in[a0];
    const float s1 = s_in[a1], r1 = r_in[a1];

    // 1-based descending rank, stable tiebreak by index (matches argsort(argsort))
    int c0 = 0, c1 = 0;
    #pragma unroll
    for (int j = 0; j < KDIM; ++j) {
        float rj0 = __uint_as_float(__builtin_amdgcn_readlane(__float_as_uint(r0), j));
        float rj1 = __uint_as_float(__builtin_amdgcn_readlane(__float_as_uint(r1), j));
        c0 += (rj0 > r0) || (rj0 == r0 && j < lane);
        c1 += (rj1 > r1) || (rj1 == r1 && j < lane);
    }
    // invd = 1/log1p(rank), rank = c+1 -> ln(c+2)
    const float invd0 = __builtin_amdgcn_rcpf(
        0.69314718056f * __builtin_amdgcn_logf((float)(c0 + 2)));
    const float invd1 = __builtin_amdgcn_rcpf(
        0.69314718056f * __builtin_amdgcn_logf((float)(c1 + 2)));
    const float g0 = 2.0f * r0 - 1.0f;
    const float g1 = 2.0f * r1 - 1.0f;

    // Rotation covering of the strict triangle: d=1..31 covers each unordered
    // pair once with all 64 lanes useful; d=32 covers each pair twice -> keep
    // lane>=32. term = delta * softplus(s_largerIdx - s_smallerIdx); final
    // answer is +sum/count.
    float p0 = 0.0f, p1 = 0.0f;
    #pragma unroll
    for (int d = 1; d <= 32; ++d) {
        const int pj = (lane - d) & 63;
        float sj0 = __shfl(s0, pj), gj0 = __shfl(g0, pj), dj0 = __shfl(invd0, pj);
        float sj1 = __shfl(s1, pj), gj1 = __shfl(g1, pj), dj1 = __shfl(invd1, pj);

        float del0 = fabsf(g0 - gj0) * fabsf(invd0 - dj0);
        float del1 = fabsf(g1 - gj1) * fabsf(invd1 - dj1);
        if (d == 32 && lane < 32) { del0 = 0.0f; del1 = 0.0f; }

        float u0 = (lane >= d) ? (s0 - sj0) : (sj0 - s0);
        float u1 = (lane >= d) ? (s1 - sj1) : (sj1 - s1);

        // softplus(u) = max(u,0) + ln2*log2(1 + 2^(-|u|*log2e))
        float e0 = __builtin_amdgcn_exp2f(-1.44269504089f * fabsf(u0));
        float e1 = __builtin_amdgcn_exp2f(-1.44269504089f * fabsf(u1));
        float sp0 = fmaxf(u0, 0.0f) + 0.69314718056f * __builtin_amdgcn_logf(1.0f + e0);
        float sp1 = fmaxf(u1, 0.0f) + 0.69314718056f * __builtin_amdgcn_logf(1.0f + e1);

        p0 = fmaf(del0, sp0, p0);
        p1 = fmaf(del1, sp1, p1);
    }
    if (row0 >= B) p0 = 0.0f;
    if (row1 >= B) p1 = 0.0f;

    float pacc = p0 + p1;
    #pragma unroll
    for (int off = 32; off > 0; off >>= 1)
        pacc += __shfl_down(pacc, off);

    __shared__ float wsum[WAVES_PER_BLOCK];
    if (lane == 0) wsum[wave] = pacc;
    __syncthreads();
    if (threadIdx.x == 0)
        partials[blockIdx.x] = wsum[0] + wsum[1] + wsum[2] + wsum[3];
}

__global__ __launch_bounds__(256) void rankdpo_reduce(
    const float* __restrict__ partials, int n, float* __restrict__ out,
    double inv_count)
{
    double sum = 0.0;
    for (int i = threadIdx.x; i < n; i += 256)
        sum += (double)partials[i];
    __shared__ double sh[256];
    sh[threadIdx.x] = sum;
    __syncthreads();
    for (int st = 128; st > 0; st >>= 1) {
        if (threadIdx.x < st) sh[threadIdx.x] += sh[threadIdx.x + st];
        __syncthreads();
    }
    if (threadIdx.x == 0)
        out[0] = (float)(sh[0] * inv_count);
}

extern "C" void kernel_launch(void* const* d_in, const int* in_sizes, int n_in,
                              void* d_out, int out_size, void* d_ws, size_t ws_size,
                              hipStream_t stream) {
    const float* s = (const float*)d_in[0];   // policy_logps [B,K] f32
    const float* r = (const float*)d_in[1];   // reward_scores [B,K] f32
    float* out = (float*)d_out;

    const int BK = in_sizes[0];
    const int B  = BK / KDIM;
    const int nblocks = (B + ROWS_PER_BLOCK - 1) / ROWS_PER_BLOCK;

    float* partials = (float*)d_ws;  // nblocks floats, all written before read

    const long long count = (long long)B * (KDIM * (KDIM - 1) / 2);
    const double inv_count = 1.0 / (double)count;

    rankdpo_main<<<nblocks, 256, 0, stream>>>(s, r, partials, B);
    rankdpo_reduce<<<1, 256, 0, stream>>>(partials, nblocks, out, inv_count);
}